// Round 17
// baseline (4522.482 us; speedup 1.0000x reference)
//
#include <hip/hip_runtime.h>
#include <math.h>

#define BB 32
#define TT 48
#define NN 360
#define HH 100
#define DD 64
#define NC 2
#define G4 400

typedef float vf4 __attribute__((ext_vector_type(4)));

__device__ __forceinline__ float sigmoid_fast(float x) {
    return 1.f / (1.f + __expf(-x));
}
__device__ __forceinline__ float tanh_fast(float x) {
    float ax = fabsf(x);
    float e = __expf(-2.f * ax);
    float t = (1.f - e) / (1.f + e);
    return copysignf(t, x);
}
__device__ __forceinline__ float bcast_lane(float v, int l) {
    return __int_as_float(__builtin_amdgcn_readlane(__float_as_int(v), l));
}
__device__ __forceinline__ vf4 ntload4(const float* p) {
    return __builtin_nontemporal_load((const vf4*)p);
}
__device__ __forceinline__ float dotslot(vf4 a, vf4 w) {
    return fmaf(a.w, w.w, fmaf(a.z, w.z, fmaf(a.y, w.y, a.x * w.x)));
}

#define DPP_ADD(x, ctrl, rmask) \
    x += __int_as_float(__builtin_amdgcn_update_dpp(0, __float_as_int(x), ctrl, rmask, 0xf, true));
#define WAVE_RED(p) \
    DPP_ADD(p, 0x111, 0xf) DPP_ADD(p, 0x112, 0xf) DPP_ADD(p, 0x114, 0xf) DPP_ADD(p, 0x118, 0xf) \
    DPP_ADD(p, 0x142, 0xa) DPP_ADD(p, 0x143, 0xc)

// ---------------- K1: GCN — R15 exact (121 µs measured, 6.5 TB/s) ----------------
#define RG 8
#define NGROUPS (BB*TT*NN/RG)        // 69120
#define GF4 (RG*NN/4)                // 720
#define LOADG(S, gidx) do { if ((gidx) < NGROUPS) { \
    const float* gb_ = x + (size_t)(gidx) * (RG * NN); \
    S##0  = ntload4(gb_ + 0*256  + 4*lane); \
    S##1  = ntload4(gb_ + 1*256  + 4*lane); \
    S##2  = ntload4(gb_ + 2*256  + 4*lane); \
    S##3  = ntload4(gb_ + 3*256  + 4*lane); \
    S##4  = ntload4(gb_ + 4*256  + 4*lane); \
    S##5  = ntload4(gb_ + 5*256  + 4*lane); \
    S##6  = ntload4(gb_ + 6*256  + 4*lane); \
    S##7  = ntload4(gb_ + 7*256  + 4*lane); \
    S##8  = ntload4(gb_ + 8*256  + 4*lane); \
    S##9  = ntload4(gb_ + 9*256  + 4*lane); \
    S##10 = ntload4(gb_ + 10*256 + 4*lane); \
    if (lane < 16) S##11 = ntload4(gb_ + 11*256 + 4*lane); \
} } while (0)
#define WRITELDS(S) do { \
    buf[0*64  + lane] = S##0; \
    buf[1*64  + lane] = S##1; \
    buf[2*64  + lane] = S##2; \
    buf[3*64  + lane] = S##3; \
    buf[4*64  + lane] = S##4; \
    buf[5*64  + lane] = S##5; \
    buf[6*64  + lane] = S##6; \
    buf[7*64  + lane] = S##7; \
    buf[8*64  + lane] = S##8; \
    buf[9*64  + lane] = S##9; \
    buf[10*64 + lane] = S##10; \
    if (lane < 16) buf[11*64 + lane] = S##11; \
} while (0)
#define COMPUTE_STORE(gcur) do { \
    float s_[RG]; \
    _Pragma("unroll") \
    for (int r = 0; r < RG; ++r) { \
        vf4 a_ = buf[r*90 + lane]; \
        float p_ = dotslot(a_, wa); \
        if (lane < 26) { vf4 a2_ = buf[r*90 + 64 + lane]; p_ += dotslot(a2_, wb); } \
        WAVE_RED(p_) \
        s_[r] = p_; \
    } \
    if (lane == 63) { \
        float4 o0_, o1_; \
        o0_.x = fmaxf(s_[0] + b, 0.f); o0_.y = fmaxf(s_[1] + b, 0.f); \
        o0_.z = fmaxf(s_[2] + b, 0.f); o0_.w = fmaxf(s_[3] + b, 0.f); \
        o1_.x = fmaxf(s_[4] + b, 0.f); o1_.y = fmaxf(s_[5] + b, 0.f); \
        o1_.z = fmaxf(s_[6] + b, 0.f); o1_.w = fmaxf(s_[7] + b, 0.f); \
        ((float4*)gout)[2*(gcur)]     = o0_; \
        ((float4*)gout)[2*(gcur) + 1] = o1_; \
    } \
} while (0)

__global__ __launch_bounds__(256) void gcn_kernel(const float* __restrict__ x,
                                                  const float* __restrict__ w,
                                                  const float* __restrict__ bptr,
                                                  float* __restrict__ gout) {
    __shared__ __align__(16) vf4 sbuf[4][GF4];
    int tid = threadIdx.x;
    int lane = tid & 63;
    int wv = tid >> 6;
    vf4* buf = sbuf[wv];
    vf4 wa = *(const vf4*)(w + 4*lane);
    vf4 wb;
    if (lane < 26) wb = *(const vf4*)(w + 4*(64 + lane));
    else { wb.x = 0.f; wb.y = 0.f; wb.z = 0.f; wb.w = 0.f; }
    float b = bptr[0];
    const int gstride = gridDim.x * 4;
    int g = blockIdx.x * 4 + wv;
    vf4 sa0, sa1, sa2, sa3, sa4, sa5, sa6, sa7, sa8, sa9, sa10, sa11;
    vf4 sb0, sb1, sb2, sb3, sb4, sb5, sb6, sb7, sb8, sb9, sb10, sb11;
    LOADG(sa, g);
    LOADG(sb, g + gstride);
    for (int g2 = g; g2 < NGROUPS; ) {
        __builtin_amdgcn_sched_barrier(0);
        WRITELDS(sa);
        LOADG(sa, g2 + 2*gstride);
        COMPUTE_STORE(g2);
        g2 += gstride;
        if (g2 >= NGROUPS) break;
        __builtin_amdgcn_sched_barrier(0);
        WRITELDS(sb);
        LOADG(sb, g2 + 2*gstride);
        COMPUTE_STORE(g2);
        g2 += gstride;
    }
}

// ---------------- K2a: transpose ----------------
__global__ void transpose_wih(const float* __restrict__ Wih, float* __restrict__ Wt2) {
    int idx = blockIdx.x * blockDim.x + threadIdx.x;
    if (idx < NN * G4) {
        int j = idx / NN, n = idx % NN;
        Wt2[n * G4 + 2 * (j % 200) + (j / 200)] = Wih[idx];
    }
}

// ---------------- K2: xproj (production) ----------------
__global__ __launch_bounds__(256) void xproj_kernel(const float* __restrict__ gout,
                                                    const float* __restrict__ Wt2,
                                                    const float* __restrict__ b_ih,
                                                    const float* __restrict__ b_hh,
                                                    float* __restrict__ xproj) {
    int tid = threadIdx.x;
    if (tid >= 200) return;
    int r0 = blockIdx.x * 4;
    float acc00 = 0.f, acc01 = 0.f, acc10 = 0.f, acc11 = 0.f;
    float acc20 = 0.f, acc21 = 0.f, acc30 = 0.f, acc31 = 0.f;
    const float* g0p = gout + (size_t)(r0 + 0) * NN;
    const float* g1p = gout + (size_t)(r0 + 1) * NN;
    const float* g2p = gout + (size_t)(r0 + 2) * NN;
    const float* g3p = gout + (size_t)(r0 + 3) * NN;
    const float* wp = Wt2 + 2 * tid;
    for (int n = 0; n < NN; n += 4) {
        float4 g0 = *(const float4*)(g0p + n);
        float4 g1 = *(const float4*)(g1p + n);
        float4 g2 = *(const float4*)(g2p + n);
        float4 g3 = *(const float4*)(g3p + n);
        float2 wA = *(const float2*)(wp + (n + 0) * G4);
        float2 wB = *(const float2*)(wp + (n + 1) * G4);
        float2 wC = *(const float2*)(wp + (n + 2) * G4);
        float2 wD = *(const float2*)(wp + (n + 3) * G4);
        acc00 += g0.x*wA.x + g0.y*wB.x + g0.z*wC.x + g0.w*wD.x;
        acc01 += g0.x*wA.y + g0.y*wB.y + g0.z*wC.y + g0.w*wD.y;
        acc10 += g1.x*wA.x + g1.y*wB.x + g1.z*wC.x + g1.w*wD.x;
        acc11 += g1.x*wA.y + g1.y*wB.y + g1.z*wC.y + g1.w*wD.y;
        acc20 += g2.x*wA.x + g2.y*wB.x + g2.z*wC.x + g2.w*wD.x;
        acc21 += g2.x*wA.y + g2.y*wB.y + g2.z*wC.y + g2.w*wD.y;
        acc30 += g3.x*wA.x + g3.y*wB.x + g3.z*wC.x + g3.w*wD.x;
        acc31 += g3.x*wA.y + g3.y*wB.y + g3.z*wC.y + g3.w*wD.y;
    }
    float bias0 = b_ih[tid] + b_hh[tid];
    float bias1 = b_ih[tid + 200] + b_hh[tid + 200];
    xproj[(size_t)(r0 + 0) * G4 + tid]       = acc00 + bias0;
    xproj[(size_t)(r0 + 0) * G4 + tid + 200] = acc01 + bias1;
    xproj[(size_t)(r0 + 1) * G4 + tid]       = acc10 + bias0;
    xproj[(size_t)(r0 + 1) * G4 + tid + 200] = acc11 + bias1;
    xproj[(size_t)(r0 + 2) * G4 + tid]       = acc20 + bias0;
    xproj[(size_t)(r0 + 2) * G4 + tid + 200] = acc21 + bias1;
    xproj[(size_t)(r0 + 3) * G4 + tid]       = acc30 + bias0;
    xproj[(size_t)(r0 + 3) * G4 + tid + 200] = acc31 + bias1;
}

// ---------------- PROBE: xproj repeated x128 (rocprof-visible) ----------------
__global__ __launch_bounds__(256) void xproj_probe(const float* __restrict__ gout,
                                                   const float* __restrict__ Wt2,
                                                   const float* __restrict__ b_ih,
                                                   const float* __restrict__ b_hh,
                                                   float* __restrict__ xp2) {
    int tid = threadIdx.x;
    if (tid >= 200) return;
    int r0 = blockIdx.x * 4;
    for (int it = 0; it < 128; ++it) {
        float acc00 = 0.f, acc01 = 0.f, acc10 = 0.f, acc11 = 0.f;
        float acc20 = 0.f, acc21 = 0.f, acc30 = 0.f, acc31 = 0.f;
        const float* g0p = gout + (size_t)(r0 + 0) * NN;
        const float* g1p = gout + (size_t)(r0 + 1) * NN;
        const float* g2p = gout + (size_t)(r0 + 2) * NN;
        const float* g3p = gout + (size_t)(r0 + 3) * NN;
        const float* wp = Wt2 + 2 * tid;
        for (int n = 0; n < NN; n += 4) {
            float4 g0 = *(const float4*)(g0p + n);
            float4 g1 = *(const float4*)(g1p + n);
            float4 g2 = *(const float4*)(g2p + n);
            float4 g3 = *(const float4*)(g3p + n);
            float2 wA = *(const float2*)(wp + (n + 0) * G4);
            float2 wB = *(const float2*)(wp + (n + 1) * G4);
            float2 wC = *(const float2*)(wp + (n + 2) * G4);
            float2 wD = *(const float2*)(wp + (n + 3) * G4);
            acc00 += g0.x*wA.x + g0.y*wB.x + g0.z*wC.x + g0.w*wD.x;
            acc01 += g0.x*wA.y + g0.y*wB.y + g0.z*wC.y + g0.w*wD.y;
            acc10 += g1.x*wA.x + g1.y*wB.x + g1.z*wC.x + g1.w*wD.x;
            acc11 += g1.x*wA.y + g1.y*wB.y + g1.z*wC.y + g1.w*wD.y;
            acc20 += g2.x*wA.x + g2.y*wB.x + g2.z*wC.x + g2.w*wD.x;
            acc21 += g2.x*wA.y + g2.y*wB.y + g2.z*wC.y + g2.w*wD.y;
            acc30 += g3.x*wA.x + g3.y*wB.x + g3.z*wC.x + g3.w*wD.x;
            acc31 += g3.x*wA.y + g3.y*wB.y + g3.z*wC.y + g3.w*wD.y;
        }
        float bias0 = b_ih[tid] + b_hh[tid];
        float bias1 = b_ih[tid + 200] + b_hh[tid + 200];
        xp2[(size_t)(r0 + 0) * G4 + tid]       = acc00 + bias0;
        xp2[(size_t)(r0 + 0) * G4 + tid + 200] = acc01 + bias1;
        xp2[(size_t)(r0 + 1) * G4 + tid]       = acc10 + bias0;
        xp2[(size_t)(r0 + 1) * G4 + tid + 200] = acc11 + bias1;
        xp2[(size_t)(r0 + 2) * G4 + tid]       = acc20 + bias0;
        xp2[(size_t)(r0 + 2) * G4 + tid + 200] = acc21 + bias1;
        xp2[(size_t)(r0 + 3) * G4 + tid]       = acc30 + bias0;
        xp2[(size_t)(r0 + 3) * G4 + tid + 200] = acc31 + bias1;
    }
}

// ---------------- K3: fused LSTM + MIL attention + classifier (production) ----------------
__global__ __launch_bounds__(448) void lstm_attn_kernel(const float* __restrict__ xproj,
                                                        const float* __restrict__ Whh,
                                                        const float* __restrict__ wa1,
                                                        const float* __restrict__ ba1,
                                                        const float* __restrict__ wa2,
                                                        const float* __restrict__ ba2,
                                                        const float* __restrict__ wc,
                                                        const float* __restrict__ bc,
                                                        float* __restrict__ out) {
    __shared__ __align__(16) float ho[TT * HH];
    __shared__ __align__(16) float h_lds[128];
    __shared__ float gates[G4];
    __shared__ float sc[TT];
    __shared__ float p[TT];
    __shared__ float M[HH];
    int b = blockIdx.x;
    int tid = threadIdx.x;
    int lane = tid & 63;
    float wr[HH];
    if (tid < G4) {
        #pragma unroll
        for (int k = 0; k < HH; k++) wr[k] = Whh[tid * HH + k];
    }
    float c = 0.f;
    if (tid < 128) h_lds[tid] = 0.f;
    float xp = (tid < G4) ? xproj[(size_t)(b * TT) * G4 + tid] : 0.f;
    __syncthreads();
    for (int t = 0; t < TT; t++) {
        float xp_next = (tid < G4 && t + 1 < TT)
                      ? xproj[(size_t)(b * TT + t + 1) * G4 + tid] : 0.f;
        float ha = h_lds[lane];
        float hb = h_lds[64 + lane];
        if (tid < G4) {
            float s0 = 0.f, s1 = 0.f, s2 = 0.f, s3 = 0.f;
            #pragma unroll
            for (int k = 0; k < 64; k += 4) {
                s0 += bcast_lane(ha, k+0) * wr[k+0];
                s1 += bcast_lane(ha, k+1) * wr[k+1];
                s2 += bcast_lane(ha, k+2) * wr[k+2];
                s3 += bcast_lane(ha, k+3) * wr[k+3];
            }
            #pragma unroll
            for (int k = 64; k < 100; k += 4) {
                s0 += bcast_lane(hb, k-64) * wr[k+0];
                s1 += bcast_lane(hb, k-63) * wr[k+1];
                s2 += bcast_lane(hb, k-62) * wr[k+2];
                s3 += bcast_lane(hb, k-61) * wr[k+3];
            }
            gates[tid] = xp + (s0 + s1) + (s2 + s3);
        }
        __syncthreads();
        if (tid < HH) {
            float ig = sigmoid_fast(gates[tid]);
            float fg = sigmoid_fast(gates[tid + HH]);
            float gg = tanh_fast(gates[tid + 2*HH]);
            float og = sigmoid_fast(gates[tid + 3*HH]);
            c = fg * c + ig * gg;
            float hh = og * tanh_fast(c);
            h_lds[tid] = hh;
            ho[t * HH + tid] = hh;
        }
        xp = xp_next;
        __syncthreads();
    }
    int wave = tid >> 6;
    for (int t = wave; t < TT; t += 7) {
        float a = 0.f;
        if (lane < DD) {
            float s = ba1[lane];
            #pragma unroll
            for (int h2 = 0; h2 < HH; h2 += 4) {
                float4 h4v = *(const float4*)&ho[t*HH + h2];
                s += wa1[lane*HH + h2+0]*h4v.x + wa1[lane*HH + h2+1]*h4v.y
                   + wa1[lane*HH + h2+2]*h4v.z + wa1[lane*HH + h2+3]*h4v.w;
            }
            a = tanh_fast(s) * wa2[lane];
        }
        #pragma unroll
        for (int off = 32; off; off >>= 1) a += __shfl_down(a, off, 64);
        if (lane == 0) sc[t] = a + ba2[0];
    }
    __syncthreads();
    if (tid < 64) {
        float v = (lane < TT) ? sc[lane] : -1e30f;
        if (lane < TT) out[BB*NC + b*TT + lane] = v;
        float m = v;
        #pragma unroll
        for (int off = 32; off; off >>= 1) m = fmaxf(m, __shfl_xor(m, off, 64));
        float e = (lane < TT) ? __expf(v - m) : 0.f;
        float s = e;
        #pragma unroll
        for (int off = 32; off; off >>= 1) s += __shfl_xor(s, off, 64);
        if (lane < TT) p[lane] = e / s;
    }
    __syncthreads();
    if (tid < HH) {
        float m = 0.f;
        #pragma unroll
        for (int t = 0; t < TT; t++) m += p[t] * ho[t*HH + tid];
        M[tid] = m;
    }
    __syncthreads();
    if (tid == 0) {
        float l0 = bc[0], l1 = bc[1];
        for (int h2 = 0; h2 < HH; h2++) { l0 += M[h2]*wc[h2]; l1 += M[h2]*wc[HH + h2]; }
        float mx = fmaxf(l0, l1);
        float e0 = __expf(l0 - mx), e1 = __expf(l1 - mx);
        float s = e0 + e1;
        out[b*NC + 0] = e0 / s;
        out[b*NC + 1] = e1 / s;
    }
}

// ---------------- PROBE: lstm_attn repeated x32 (rocprof-visible) ----------------
__global__ __launch_bounds__(448) void lstm_probe(const float* __restrict__ xproj,
                                                  const float* __restrict__ Whh,
                                                  const float* __restrict__ wa1,
                                                  const float* __restrict__ ba1,
                                                  const float* __restrict__ wa2,
                                                  const float* __restrict__ ba2,
                                                  const float* __restrict__ wc,
                                                  const float* __restrict__ bc,
                                                  float* __restrict__ pout) {
    __shared__ __align__(16) float ho[TT * HH];
    __shared__ __align__(16) float h_lds[128];
    __shared__ float gates[G4];
    __shared__ float sc[TT];
    __shared__ float p[TT];
    __shared__ float M[HH];
    int b = blockIdx.x;
    int tid = threadIdx.x;
    int lane = tid & 63;
    float wr[HH];
    if (tid < G4) {
        #pragma unroll
        for (int k = 0; k < HH; k++) wr[k] = Whh[tid * HH + k];
    }
    for (int it = 0; it < 32; ++it) {
        float c = 0.f;
        if (tid < 128) h_lds[tid] = 0.f;
        float xp = (tid < G4) ? xproj[(size_t)(b * TT) * G4 + tid] : 0.f;
        __syncthreads();
        for (int t = 0; t < TT; t++) {
            float xp_next = (tid < G4 && t + 1 < TT)
                          ? xproj[(size_t)(b * TT + t + 1) * G4 + tid] : 0.f;
            float ha = h_lds[lane];
            float hb = h_lds[64 + lane];
            if (tid < G4) {
                float s0 = 0.f, s1 = 0.f, s2 = 0.f, s3 = 0.f;
                #pragma unroll
                for (int k = 0; k < 64; k += 4) {
                    s0 += bcast_lane(ha, k+0) * wr[k+0];
                    s1 += bcast_lane(ha, k+1) * wr[k+1];
                    s2 += bcast_lane(ha, k+2) * wr[k+2];
                    s3 += bcast_lane(ha, k+3) * wr[k+3];
                }
                #pragma unroll
                for (int k = 64; k < 100; k += 4) {
                    s0 += bcast_lane(hb, k-64) * wr[k+0];
                    s1 += bcast_lane(hb, k-63) * wr[k+1];
                    s2 += bcast_lane(hb, k-62) * wr[k+2];
                    s3 += bcast_lane(hb, k-61) * wr[k+3];
                }
                gates[tid] = xp + (s0 + s1) + (s2 + s3);
            }
            __syncthreads();
            if (tid < HH) {
                float ig = sigmoid_fast(gates[tid]);
                float fg = sigmoid_fast(gates[tid + HH]);
                float gg = tanh_fast(gates[tid + 2*HH]);
                float og = sigmoid_fast(gates[tid + 3*HH]);
                c = fg * c + ig * gg;
                float hh = og * tanh_fast(c);
                h_lds[tid] = hh;
                ho[t * HH + tid] = hh;
            }
            xp = xp_next;
            __syncthreads();
        }
        int wave = tid >> 6;
        for (int t = wave; t < TT; t += 7) {
            float a = 0.f;
            if (lane < DD) {
                float s = ba1[lane];
                #pragma unroll
                for (int h2 = 0; h2 < HH; h2 += 4) {
                    float4 h4v = *(const float4*)&ho[t*HH + h2];
                    s += wa1[lane*HH + h2+0]*h4v.x + wa1[lane*HH + h2+1]*h4v.y
                       + wa1[lane*HH + h2+2]*h4v.z + wa1[lane*HH + h2+3]*h4v.w;
                }
                a = tanh_fast(s) * wa2[lane];
            }
            #pragma unroll
            for (int off = 32; off; off >>= 1) a += __shfl_down(a, off, 64);
            if (lane == 0) sc[t] = a + ba2[0];
        }
        __syncthreads();
        if (tid < 64) {
            float v = (lane < TT) ? sc[lane] : -1e30f;
            if (lane < TT) pout[BB*NC + b*TT + lane] = v;
            float m = v;
            #pragma unroll
            for (int off = 32; off; off >>= 1) m = fmaxf(m, __shfl_xor(m, off, 64));
            float e = (lane < TT) ? __expf(v - m) : 0.f;
            float s = e;
            #pragma unroll
            for (int off = 32; off; off >>= 1) s += __shfl_xor(s, off, 64);
            if (lane < TT) p[lane] = e / s;
        }
        __syncthreads();
        if (tid < HH) {
            float m = 0.f;
            #pragma unroll
            for (int t = 0; t < TT; t++) m += p[t] * ho[t*HH + tid];
            M[tid] = m;
        }
        __syncthreads();
        if (tid == 0) {
            float l0 = bc[0], l1 = bc[1];
            for (int h2 = 0; h2 < HH; h2++) { l0 += M[h2]*wc[h2]; l1 += M[h2]*wc[HH + h2]; }
            float mx = fmaxf(l0, l1);
            float e0 = __expf(l0 - mx), e1 = __expf(l1 - mx);
            float s = e0 + e1;
            pout[b*NC + 0] = e0 / s;
            pout[b*NC + 1] = e1 / s;
        }
        __syncthreads();
    }
}

extern "C" void kernel_launch(void* const* d_in, const int* in_sizes, int n_in,
                              void* d_out, int out_size, void* d_ws, size_t ws_size,
                              hipStream_t stream) {
    const float* x     = (const float*)d_in[0];
    const float* w_gcn = (const float*)d_in[1];
    const float* b_gcn = (const float*)d_in[2];
    const float* W_ih  = (const float*)d_in[3];
    const float* W_hh  = (const float*)d_in[4];
    const float* b_ih  = (const float*)d_in[5];
    const float* b_hh  = (const float*)d_in[6];
    const float* wa1   = (const float*)d_in[7];
    const float* ba1   = (const float*)d_in[8];
    const float* wa2   = (const float*)d_in[9];
    const float* ba2   = (const float*)d_in[10];
    const float* wc    = (const float*)d_in[11];
    const float* bc    = (const float*)d_in[12];
    float* out = (float*)d_out;
    float* ws  = (float*)d_ws;

    float* gout  = ws;                       // 552960 floats
    float* Wt2   = gout + 552960;            // 144000 floats
    float* xproj = Wt2 + 144000;             // 614400 floats
    float* xp2   = xproj + 614400;           // 614400 floats (probe scratch)
    float* pout  = xp2 + 614400;             // 2048 floats (probe scratch)

    transpose_wih<<<(NN*G4 + 255)/256, 256, 0, stream>>>(W_ih, Wt2);
    gcn_kernel<<<768, 256, 0, stream>>>(x, w_gcn, b_gcn, gout);
    xproj_kernel<<<384, 256, 0, stream>>>(gout, Wt2, b_ih, b_hh, xproj);
    lstm_attn_kernel<<<BB, 448, 0, stream>>>(xproj, W_hh, wa1, ba1, wa2, ba2, wc, bc, out);
    // PROBES (outputs unused downstream; durations read from rocprof table)
    xproj_probe<<<384, 256, 0, stream>>>(gout, Wt2, b_ih, b_hh, xp2);
    lstm_probe<<<BB, 448, 0, stream>>>(xproj, W_hh, wa1, ba1, wa2, ba2, wc, bc, pout);
}

// Round 19
// 213.008 us; speedup vs baseline: 21.2315x; 21.2315x over previous
//
#include <hip/hip_runtime.h>
#include <math.h>

#define BB 32
#define TT 48
#define NN 360
#define HH 100
#define DD 64
#define NC 2
#define G4 400

typedef float vf4 __attribute__((ext_vector_type(4)));

__device__ __forceinline__ float sigmoid_fast(float x) {
    return 1.f / (1.f + __expf(-x));
}
__device__ __forceinline__ float tanh_fast(float x) {
    float ax = fabsf(x);
    float e = __expf(-2.f * ax);
    float t = (1.f - e) / (1.f + e);
    return copysignf(t, x);
}
__device__ __forceinline__ float bcast_lane(float v, int l) {
    return __int_as_float(__builtin_amdgcn_readlane(__float_as_int(v), l));
}
template <int CTRL>
__device__ __forceinline__ float quad_bcast(float v) {
    // DPP quad_perm broadcast within each 4-lane quad; CTRL 0x00/0x55/0xAA/0xFF
    return __int_as_float(__builtin_amdgcn_update_dpp(0, __float_as_int(v), CTRL, 0xf, 0xf, true));
}
__device__ __forceinline__ vf4 ntload4(const float* p) {
    return __builtin_nontemporal_load((const vf4*)p);
}
__device__ __forceinline__ float dotslot(vf4 a, vf4 w) {
    return fmaf(a.w, w.w, fmaf(a.z, w.z, fmaf(a.y, w.y, a.x * w.x)));
}

#define DPP_ADD(x, ctrl, rmask) \
    x += __int_as_float(__builtin_amdgcn_update_dpp(0, __float_as_int(x), ctrl, rmask, 0xf, true));
#define WAVE_RED(p) \
    DPP_ADD(p, 0x111, 0xf) DPP_ADD(p, 0x112, 0xf) DPP_ADD(p, 0x114, 0xf) DPP_ADD(p, 0x118, 0xf) \
    DPP_ADD(p, 0x142, 0xa) DPP_ADD(p, 0x143, 0xc)

// ---------------- K1: GCN — R15 exact (121 µs measured, 6.5 TB/s) ----------------
#define RG 8
#define NGROUPS (BB*TT*NN/RG)        // 69120
#define GF4 (RG*NN/4)                // 720
#define LOADG(S, gidx) do { if ((gidx) < NGROUPS) { \
    const float* gb_ = x + (size_t)(gidx) * (RG * NN); \
    S##0  = ntload4(gb_ + 0*256  + 4*lane); \
    S##1  = ntload4(gb_ + 1*256  + 4*lane); \
    S##2  = ntload4(gb_ + 2*256  + 4*lane); \
    S##3  = ntload4(gb_ + 3*256  + 4*lane); \
    S##4  = ntload4(gb_ + 4*256  + 4*lane); \
    S##5  = ntload4(gb_ + 5*256  + 4*lane); \
    S##6  = ntload4(gb_ + 6*256  + 4*lane); \
    S##7  = ntload4(gb_ + 7*256  + 4*lane); \
    S##8  = ntload4(gb_ + 8*256  + 4*lane); \
    S##9  = ntload4(gb_ + 9*256  + 4*lane); \
    S##10 = ntload4(gb_ + 10*256 + 4*lane); \
    if (lane < 16) S##11 = ntload4(gb_ + 11*256 + 4*lane); \
} } while (0)
#define WRITELDS(S) do { \
    buf[0*64  + lane] = S##0; \
    buf[1*64  + lane] = S##1; \
    buf[2*64  + lane] = S##2; \
    buf[3*64  + lane] = S##3; \
    buf[4*64  + lane] = S##4; \
    buf[5*64  + lane] = S##5; \
    buf[6*64  + lane] = S##6; \
    buf[7*64  + lane] = S##7; \
    buf[8*64  + lane] = S##8; \
    buf[9*64  + lane] = S##9; \
    buf[10*64 + lane] = S##10; \
    if (lane < 16) buf[11*64 + lane] = S##11; \
} while (0)
#define COMPUTE_STORE(gcur) do { \
    float s_[RG]; \
    _Pragma("unroll") \
    for (int r = 0; r < RG; ++r) { \
        vf4 a_ = buf[r*90 + lane]; \
        float p_ = dotslot(a_, wa); \
        if (lane < 26) { vf4 a2_ = buf[r*90 + 64 + lane]; p_ += dotslot(a2_, wb); } \
        WAVE_RED(p_) \
        s_[r] = p_; \
    } \
    if (lane == 63) { \
        float4 o0_, o1_; \
        o0_.x = fmaxf(s_[0] + b, 0.f); o0_.y = fmaxf(s_[1] + b, 0.f); \
        o0_.z = fmaxf(s_[2] + b, 0.f); o0_.w = fmaxf(s_[3] + b, 0.f); \
        o1_.x = fmaxf(s_[4] + b, 0.f); o1_.y = fmaxf(s_[5] + b, 0.f); \
        o1_.z = fmaxf(s_[6] + b, 0.f); o1_.w = fmaxf(s_[7] + b, 0.f); \
        ((float4*)gout)[2*(gcur)]     = o0_; \
        ((float4*)gout)[2*(gcur) + 1] = o1_; \
    } \
} while (0)

__global__ __launch_bounds__(256) void gcn_kernel(const float* __restrict__ x,
                                                  const float* __restrict__ w,
                                                  const float* __restrict__ bptr,
                                                  float* __restrict__ gout) {
    __shared__ __align__(16) vf4 sbuf[4][GF4];
    int tid = threadIdx.x;
    int lane = tid & 63;
    int wv = tid >> 6;
    vf4* buf = sbuf[wv];
    vf4 wa = *(const vf4*)(w + 4*lane);
    vf4 wb;
    if (lane < 26) wb = *(const vf4*)(w + 4*(64 + lane));
    else { wb.x = 0.f; wb.y = 0.f; wb.z = 0.f; wb.w = 0.f; }
    float b = bptr[0];
    const int gstride = gridDim.x * 4;
    int g = blockIdx.x * 4 + wv;
    vf4 sa0, sa1, sa2, sa3, sa4, sa5, sa6, sa7, sa8, sa9, sa10, sa11;
    vf4 sb0, sb1, sb2, sb3, sb4, sb5, sb6, sb7, sb8, sb9, sb10, sb11;
    LOADG(sa, g);
    LOADG(sb, g + gstride);
    for (int g2 = g; g2 < NGROUPS; ) {
        __builtin_amdgcn_sched_barrier(0);
        WRITELDS(sa);
        LOADG(sa, g2 + 2*gstride);
        COMPUTE_STORE(g2);
        g2 += gstride;
        if (g2 >= NGROUPS) break;
        __builtin_amdgcn_sched_barrier(0);
        WRITELDS(sb);
        LOADG(sb, g2 + 2*gstride);
        COMPUTE_STORE(g2);
        g2 += gstride;
    }
}

// ---------------- K2a: plain transpose W_ih [400,360] -> Wt [360,400] ----------------
__global__ void transpose_wih(const float* __restrict__ Wih, float* __restrict__ Wt) {
    int idx = blockIdx.x * blockDim.x + threadIdx.x;
    if (idx < NN * G4) {
        int j = idx / NN, n = idx % NN;
        Wt[n * G4 + j] = Wih[idx];
    }
}

// ---------------- K2: xproj — 400 active threads (1 col each), permuted output ----------------
// Output written in quad-gate order: col (g*100+j) -> slot (4*j+g), so the lstm
// kernel's per-thread loads stay linear/coalesced.
__global__ __launch_bounds__(448) void xproj_kernel(const float* __restrict__ gout,
                                                    const float* __restrict__ Wt,
                                                    const float* __restrict__ b_ih,
                                                    const float* __restrict__ b_hh,
                                                    float* __restrict__ xproj) {
    int tid = threadIdx.x;
    if (tid >= G4) return;
    int r0 = blockIdx.x * 4;
    float a0 = 0.f, a1 = 0.f, a2 = 0.f, a3 = 0.f;
    const float* g0p = gout + (size_t)(r0 + 0) * NN;
    const float* g1p = gout + (size_t)(r0 + 1) * NN;
    const float* g2p = gout + (size_t)(r0 + 2) * NN;
    const float* g3p = gout + (size_t)(r0 + 3) * NN;
    const float* wp = Wt + tid;
    for (int n = 0; n < NN; n += 4) {
        float w0 = wp[(n+0)*G4];
        float w1 = wp[(n+1)*G4];
        float w2 = wp[(n+2)*G4];
        float w3 = wp[(n+3)*G4];
        float4 g0 = *(const float4*)(g0p + n);
        float4 g1 = *(const float4*)(g1p + n);
        float4 g2 = *(const float4*)(g2p + n);
        float4 g3 = *(const float4*)(g3p + n);
        a0 += g0.x*w0 + g0.y*w1 + g0.z*w2 + g0.w*w3;
        a1 += g1.x*w0 + g1.y*w1 + g1.z*w2 + g1.w*w3;
        a2 += g2.x*w0 + g2.y*w1 + g2.z*w2 + g2.w*w3;
        a3 += g3.x*w0 + g3.y*w1 + g3.z*w2 + g3.w*w3;
    }
    float bias = b_ih[tid] + b_hh[tid];
    int pj = 4 * (tid % HH) + (tid / HH);       // permuted slot
    xproj[(size_t)(r0 + 0) * G4 + pj] = a0 + bias;
    xproj[(size_t)(r0 + 1) * G4 + pj] = a1 + bias;
    xproj[(size_t)(r0 + 2) * G4 + pj] = a2 + bias;
    xproj[(size_t)(r0 + 3) * G4 + pj] = a3 + bias;
}

// ---------------- K3: fused LSTM + attention — quad-gate layout, 1 barrier/step ----------------
// Thread tid (<400): gate g = tid&3 (i,f,g,o), unit j = tid>>2. The 4 gates of
// unit j live in one lane-quad -> exchanged via DPP quad_perm (no LDS, no
// barrier). h double-buffered in LDS -> ONE barrier per step.
__global__ __launch_bounds__(448) void lstm_attn_kernel(const float* __restrict__ xproj,
                                                        const float* __restrict__ Whh,
                                                        const float* __restrict__ wa1,
                                                        const float* __restrict__ ba1,
                                                        const float* __restrict__ wa2,
                                                        const float* __restrict__ ba2,
                                                        const float* __restrict__ wc,
                                                        const float* __restrict__ bc,
                                                        float* __restrict__ out) {
    __shared__ __align__(16) float ho[TT * HH];    // 19.2 KB
    __shared__ __align__(16) float hbuf[2][128];   // double-buffered h
    __shared__ float sc[TT];
    __shared__ float p[TT];
    __shared__ float M[HH];
    int b = blockIdx.x;
    int tid = threadIdx.x;
    int lane = tid & 63;
    int g = tid & 3;
    int j = tid >> 2;                 // unit, valid for tid<400
    float wr[HH];
    if (tid < G4) {
        int row = g * HH + j;         // pytorch gate-row
        #pragma unroll
        for (int k = 0; k < HH; k++) wr[k] = Whh[row * HH + k];
    }
    float c = 0.f;
    if (tid < 128) { hbuf[0][tid] = 0.f; hbuf[1][tid] = 0.f; }
    float xp = (tid < G4) ? xproj[(size_t)(b * TT) * G4 + tid] : 0.f;
    __syncthreads();
    for (int t = 0; t < TT; t++) {
        int pcur = t & 1;
        float xp_next = (tid < G4 && t + 1 < TT)
                      ? xproj[(size_t)(b * TT + t + 1) * G4 + tid] : 0.f;
        float ha = hbuf[pcur][lane];
        float hb = hbuf[pcur][64 + lane];
        float v = xp;
        if (tid < G4) {
            float s0 = 0.f, s1 = 0.f, s2 = 0.f, s3 = 0.f;
            #pragma unroll
            for (int k = 0; k < 64; k += 4) {
                s0 += bcast_lane(ha, k+0) * wr[k+0];
                s1 += bcast_lane(ha, k+1) * wr[k+1];
                s2 += bcast_lane(ha, k+2) * wr[k+2];
                s3 += bcast_lane(ha, k+3) * wr[k+3];
            }
            #pragma unroll
            for (int k = 64; k < 100; k += 4) {
                s0 += bcast_lane(hb, k-64) * wr[k+0];
                s1 += bcast_lane(hb, k-63) * wr[k+1];
                s2 += bcast_lane(hb, k-62) * wr[k+2];
                s3 += bcast_lane(hb, k-61) * wr[k+3];
            }
            v = xp + (s0 + s1) + (s2 + s3);
        }
        // quad exchange: every lane gets its quad's 4 gate pre-activations
        float vi = quad_bcast<0x00>(v);
        float vf = quad_bcast<0x55>(v);
        float vg = quad_bcast<0xAA>(v);
        float vo = quad_bcast<0xFF>(v);
        if (tid < G4 && g == 0) {
            float ig = sigmoid_fast(vi);
            float fg = sigmoid_fast(vf);
            float gg = tanh_fast(vg);
            float og = sigmoid_fast(vo);
            c = fg * c + ig * gg;
            float hh = og * tanh_fast(c);
            hbuf[1 - pcur][j] = hh;
            ho[t * HH + j] = hh;
        }
        xp = xp_next;
        __syncthreads();
    }
    // ---- MIL attention ----
    int wave = tid >> 6;
    for (int t = wave; t < TT; t += 7) {
        float a = 0.f;
        if (lane < DD) {
            float s = ba1[lane];
            #pragma unroll
            for (int h2 = 0; h2 < HH; h2 += 4) {
                float4 h4v = *(const float4*)&ho[t*HH + h2];
                s += wa1[lane*HH + h2+0]*h4v.x + wa1[lane*HH + h2+1]*h4v.y
                   + wa1[lane*HH + h2+2]*h4v.z + wa1[lane*HH + h2+3]*h4v.w;
            }
            a = tanh_fast(s) * wa2[lane];
        }
        #pragma unroll
        for (int off = 32; off; off >>= 1) a += __shfl_down(a, off, 64);
        if (lane == 0) sc[t] = a + ba2[0];
    }
    __syncthreads();
    if (tid < 64) {
        float v = (lane < TT) ? sc[lane] : -1e30f;
        if (lane < TT) out[BB*NC + b*TT + lane] = v;      // Att (pre-softmax logits)
        float m = v;
        #pragma unroll
        for (int off = 32; off; off >>= 1) m = fmaxf(m, __shfl_xor(m, off, 64));
        float e = (lane < TT) ? __expf(v - m) : 0.f;
        float s = e;
        #pragma unroll
        for (int off = 32; off; off >>= 1) s += __shfl_xor(s, off, 64);
        if (lane < TT) p[lane] = e / s;
    }
    __syncthreads();
    if (tid < HH) {
        float m = 0.f;
        #pragma unroll
        for (int t = 0; t < TT; t++) m += p[t] * ho[t*HH + tid];
        M[tid] = m;
    }
    __syncthreads();
    if (tid == 0) {
        float l0 = bc[0], l1 = bc[1];
        for (int h2 = 0; h2 < HH; h2++) { l0 += M[h2]*wc[h2]; l1 += M[h2]*wc[HH + h2]; }
        float mx = fmaxf(l0, l1);
        float e0 = __expf(l0 - mx), e1 = __expf(l1 - mx);
        float s = e0 + e1;
        out[b*NC + 0] = e0 / s;
        out[b*NC + 1] = e1 / s;
    }
}

extern "C" void kernel_launch(void* const* d_in, const int* in_sizes, int n_in,
                              void* d_out, int out_size, void* d_ws, size_t ws_size,
                              hipStream_t stream) {
    const float* x     = (const float*)d_in[0];
    const float* w_gcn = (const float*)d_in[1];
    const float* b_gcn = (const float*)d_in[2];
    const float* W_ih  = (const float*)d_in[3];
    const float* W_hh  = (const float*)d_in[4];
    const float* b_ih  = (const float*)d_in[5];
    const float* b_hh  = (const float*)d_in[6];
    const float* wa1   = (const float*)d_in[7];
    const float* ba1   = (const float*)d_in[8];
    const float* wa2   = (const float*)d_in[9];
    const float* ba2   = (const float*)d_in[10];
    const float* wc    = (const float*)d_in[11];
    const float* bc    = (const float*)d_in[12];
    float* out = (float*)d_out;
    float* ws  = (float*)d_ws;

    float* gout  = ws;                       // 552960 floats
    float* Wt    = gout + 552960;            // 144000 floats
    float* xproj = Wt + 144000;              // 614400 floats

    transpose_wih<<<(NN*G4 + 255)/256, 256, 0, stream>>>(W_ih, Wt);
    gcn_kernel<<<768, 256, 0, stream>>>(x, w_gcn, b_gcn, gout);
    xproj_kernel<<<384, 448, 0, stream>>>(gout, Wt, b_ih, b_hh, xproj);
    lstm_attn_kernel<<<BB, 448, 0, stream>>>(xproj, W_hh, wa1, ba1, wa2, ba2, wc, bc, out);
}

// Round 20
// 210.440 us; speedup vs baseline: 21.4906x; 1.0122x over previous
//
#include <hip/hip_runtime.h>
#include <math.h>

#define BB 32
#define TT 48
#define NN 360
#define HH 100
#define DD 64
#define NC 2
#define G4 400

typedef float vf4 __attribute__((ext_vector_type(4)));

__device__ __forceinline__ float sigmoid_fast(float x) {
    return 1.f / (1.f + __expf(-x));
}
__device__ __forceinline__ float tanh_fast(float x) {
    float ax = fabsf(x);
    float e = __expf(-2.f * ax);
    float t = (1.f - e) / (1.f + e);
    return copysignf(t, x);
}
__device__ __forceinline__ float bcast_lane(float v, int l) {
    return __int_as_float(__builtin_amdgcn_readlane(__float_as_int(v), l));
}
template <int CTRL>
__device__ __forceinline__ float quad_bcast(float v) {
    return __int_as_float(__builtin_amdgcn_update_dpp(0, __float_as_int(v), CTRL, 0xf, 0xf, true));
}
__device__ __forceinline__ vf4 ntload4(const float* p) {
    return __builtin_nontemporal_load((const vf4*)p);
}
__device__ __forceinline__ float dotslot(vf4 a, vf4 w) {
    return fmaf(a.w, w.w, fmaf(a.z, w.z, fmaf(a.y, w.y, a.x * w.x)));
}

#define DPP_ADD(x, ctrl, rmask) \
    x += __int_as_float(__builtin_amdgcn_update_dpp(0, __float_as_int(x), ctrl, rmask, 0xf, true));
#define WAVE_RED(p) \
    DPP_ADD(p, 0x111, 0xf) DPP_ADD(p, 0x112, 0xf) DPP_ADD(p, 0x114, 0xf) DPP_ADD(p, 0x118, 0xf) \
    DPP_ADD(p, 0x142, 0xa) DPP_ADD(p, 0x143, 0xc)

// ---------------- K1: GCN — R15 exact (121 µs measured, 6.5 TB/s) ----------------
#define RG 8
#define NGROUPS (BB*TT*NN/RG)        // 69120
#define GF4 (RG*NN/4)                // 720
#define LOADG(S, gidx) do { if ((gidx) < NGROUPS) { \
    const float* gb_ = x + (size_t)(gidx) * (RG * NN); \
    S##0  = ntload4(gb_ + 0*256  + 4*lane); \
    S##1  = ntload4(gb_ + 1*256  + 4*lane); \
    S##2  = ntload4(gb_ + 2*256  + 4*lane); \
    S##3  = ntload4(gb_ + 3*256  + 4*lane); \
    S##4  = ntload4(gb_ + 4*256  + 4*lane); \
    S##5  = ntload4(gb_ + 5*256  + 4*lane); \
    S##6  = ntload4(gb_ + 6*256  + 4*lane); \
    S##7  = ntload4(gb_ + 7*256  + 4*lane); \
    S##8  = ntload4(gb_ + 8*256  + 4*lane); \
    S##9  = ntload4(gb_ + 9*256  + 4*lane); \
    S##10 = ntload4(gb_ + 10*256 + 4*lane); \
    if (lane < 16) S##11 = ntload4(gb_ + 11*256 + 4*lane); \
} } while (0)
#define WRITELDS(S) do { \
    buf[0*64  + lane] = S##0; \
    buf[1*64  + lane] = S##1; \
    buf[2*64  + lane] = S##2; \
    buf[3*64  + lane] = S##3; \
    buf[4*64  + lane] = S##4; \
    buf[5*64  + lane] = S##5; \
    buf[6*64  + lane] = S##6; \
    buf[7*64  + lane] = S##7; \
    buf[8*64  + lane] = S##8; \
    buf[9*64  + lane] = S##9; \
    buf[10*64 + lane] = S##10; \
    if (lane < 16) buf[11*64 + lane] = S##11; \
} while (0)
#define COMPUTE_STORE(gcur) do { \
    float s_[RG]; \
    _Pragma("unroll") \
    for (int r = 0; r < RG; ++r) { \
        vf4 a_ = buf[r*90 + lane]; \
        float p_ = dotslot(a_, wa); \
        if (lane < 26) { vf4 a2_ = buf[r*90 + 64 + lane]; p_ += dotslot(a2_, wb); } \
        WAVE_RED(p_) \
        s_[r] = p_; \
    } \
    if (lane == 63) { \
        float4 o0_, o1_; \
        o0_.x = fmaxf(s_[0] + b, 0.f); o0_.y = fmaxf(s_[1] + b, 0.f); \
        o0_.z = fmaxf(s_[2] + b, 0.f); o0_.w = fmaxf(s_[3] + b, 0.f); \
        o1_.x = fmaxf(s_[4] + b, 0.f); o1_.y = fmaxf(s_[5] + b, 0.f); \
        o1_.z = fmaxf(s_[6] + b, 0.f); o1_.w = fmaxf(s_[7] + b, 0.f); \
        ((float4*)gout)[2*(gcur)]     = o0_; \
        ((float4*)gout)[2*(gcur) + 1] = o1_; \
    } \
} while (0)

__global__ __launch_bounds__(256) void gcn_kernel(const float* __restrict__ x,
                                                  const float* __restrict__ w,
                                                  const float* __restrict__ bptr,
                                                  float* __restrict__ gout) {
    __shared__ __align__(16) vf4 sbuf[4][GF4];
    int tid = threadIdx.x;
    int lane = tid & 63;
    int wv = tid >> 6;
    vf4* buf = sbuf[wv];
    vf4 wa = *(const vf4*)(w + 4*lane);
    vf4 wb;
    if (lane < 26) wb = *(const vf4*)(w + 4*(64 + lane));
    else { wb.x = 0.f; wb.y = 0.f; wb.z = 0.f; wb.w = 0.f; }
    float b = bptr[0];
    const int gstride = gridDim.x * 4;
    int g = blockIdx.x * 4 + wv;
    vf4 sa0, sa1, sa2, sa3, sa4, sa5, sa6, sa7, sa8, sa9, sa10, sa11;
    vf4 sb0, sb1, sb2, sb3, sb4, sb5, sb6, sb7, sb8, sb9, sb10, sb11;
    LOADG(sa, g);
    LOADG(sb, g + gstride);
    for (int g2 = g; g2 < NGROUPS; ) {
        __builtin_amdgcn_sched_barrier(0);
        WRITELDS(sa);
        LOADG(sa, g2 + 2*gstride);
        COMPUTE_STORE(g2);
        g2 += gstride;
        if (g2 >= NGROUPS) break;
        __builtin_amdgcn_sched_barrier(0);
        WRITELDS(sb);
        LOADG(sb, g2 + 2*gstride);
        COMPUTE_STORE(g2);
        g2 += gstride;
    }
}

// ---------------- K2a: transpose W_ih -> Wt AND wa1 -> wa1T ----------------
__global__ void transpose_kernel(const float* __restrict__ Wih, float* __restrict__ Wt,
                                 const float* __restrict__ wa1, float* __restrict__ wa1T) {
    int idx = blockIdx.x * blockDim.x + threadIdx.x;
    if (idx < NN * G4) {
        int j = idx / NN, n = idx % NN;
        Wt[n * G4 + j] = Wih[idx];
    } else if (idx < NN * G4 + DD * HH) {
        int k = idx - NN * G4;
        int d = k / HH, h = k % HH;
        wa1T[h * DD + d] = wa1[k];
    }
}

// ---------------- K2: xproj — 400 active threads, permuted output (R19) ----------------
__global__ __launch_bounds__(448) void xproj_kernel(const float* __restrict__ gout,
                                                    const float* __restrict__ Wt,
                                                    const float* __restrict__ b_ih,
                                                    const float* __restrict__ b_hh,
                                                    float* __restrict__ xproj) {
    int tid = threadIdx.x;
    if (tid >= G4) return;
    int r0 = blockIdx.x * 4;
    float a0 = 0.f, a1 = 0.f, a2 = 0.f, a3 = 0.f;
    const float* g0p = gout + (size_t)(r0 + 0) * NN;
    const float* g1p = gout + (size_t)(r0 + 1) * NN;
    const float* g2p = gout + (size_t)(r0 + 2) * NN;
    const float* g3p = gout + (size_t)(r0 + 3) * NN;
    const float* wp = Wt + tid;
    for (int n = 0; n < NN; n += 4) {
        float w0 = wp[(n+0)*G4];
        float w1 = wp[(n+1)*G4];
        float w2 = wp[(n+2)*G4];
        float w3 = wp[(n+3)*G4];
        float4 g0 = *(const float4*)(g0p + n);
        float4 g1 = *(const float4*)(g1p + n);
        float4 g2 = *(const float4*)(g2p + n);
        float4 g3 = *(const float4*)(g3p + n);
        a0 += g0.x*w0 + g0.y*w1 + g0.z*w2 + g0.w*w3;
        a1 += g1.x*w0 + g1.y*w1 + g1.z*w2 + g1.w*w3;
        a2 += g2.x*w0 + g2.y*w1 + g2.z*w2 + g2.w*w3;
        a3 += g3.x*w0 + g3.y*w1 + g3.z*w2 + g3.w*w3;
    }
    float bias = b_ih[tid] + b_hh[tid];
    int pj = 4 * (tid % HH) + (tid / HH);       // permuted slot (quad-gate order)
    xproj[(size_t)(r0 + 0) * G4 + pj] = a0 + bias;
    xproj[(size_t)(r0 + 1) * G4 + pj] = a1 + bias;
    xproj[(size_t)(r0 + 2) * G4 + pj] = a2 + bias;
    xproj[(size_t)(r0 + 3) * G4 + pj] = a3 + bias;
}

// ---------------- K3: fused LSTM + attention — quad-gate, coalesced wa1T, parallel classifier ----------------
__global__ __launch_bounds__(448) void lstm_attn_kernel(const float* __restrict__ xproj,
                                                        const float* __restrict__ Whh,
                                                        const float* __restrict__ wa1T,
                                                        const float* __restrict__ ba1,
                                                        const float* __restrict__ wa2,
                                                        const float* __restrict__ ba2,
                                                        const float* __restrict__ wc,
                                                        const float* __restrict__ bc,
                                                        float* __restrict__ out) {
    __shared__ __align__(16) float ho[TT * HH];    // 19.2 KB
    __shared__ __align__(16) float hbuf[2][128];
    __shared__ float sc[TT];
    __shared__ float p[TT];
    __shared__ float M[HH];
    int b = blockIdx.x;
    int tid = threadIdx.x;
    int lane = tid & 63;
    int g = tid & 3;
    int j = tid >> 2;
    float wr[HH];
    if (tid < G4) {
        int row = g * HH + j;
        #pragma unroll
        for (int k = 0; k < HH; k++) wr[k] = Whh[row * HH + k];
    }
    float c = 0.f;
    if (tid < 128) { hbuf[0][tid] = 0.f; hbuf[1][tid] = 0.f; }
    float xp = (tid < G4) ? xproj[(size_t)(b * TT) * G4 + tid] : 0.f;
    __syncthreads();
    for (int t = 0; t < TT; t++) {
        int pcur = t & 1;
        float xp_next = (tid < G4 && t + 1 < TT)
                      ? xproj[(size_t)(b * TT + t + 1) * G4 + tid] : 0.f;
        float ha = hbuf[pcur][lane];
        float hb = hbuf[pcur][64 + lane];
        float v = xp;
        if (tid < G4) {
            float s0 = 0.f, s1 = 0.f, s2 = 0.f, s3 = 0.f;
            #pragma unroll
            for (int k = 0; k < 64; k += 4) {
                s0 += bcast_lane(ha, k+0) * wr[k+0];
                s1 += bcast_lane(ha, k+1) * wr[k+1];
                s2 += bcast_lane(ha, k+2) * wr[k+2];
                s3 += bcast_lane(ha, k+3) * wr[k+3];
            }
            #pragma unroll
            for (int k = 64; k < 100; k += 4) {
                s0 += bcast_lane(hb, k-64) * wr[k+0];
                s1 += bcast_lane(hb, k-63) * wr[k+1];
                s2 += bcast_lane(hb, k-62) * wr[k+2];
                s3 += bcast_lane(hb, k-61) * wr[k+3];
            }
            v = xp + (s0 + s1) + (s2 + s3);
        }
        float vi = quad_bcast<0x00>(v);
        float vf = quad_bcast<0x55>(v);
        float vg = quad_bcast<0xAA>(v);
        float vo = quad_bcast<0xFF>(v);
        if (tid < G4 && g == 0) {
            float ig = sigmoid_fast(vi);
            float fg = sigmoid_fast(vf);
            float gg = tanh_fast(vg);
            float og = sigmoid_fast(vo);
            c = fg * c + ig * gg;
            float hh = og * tanh_fast(c);
            hbuf[1 - pcur][j] = hh;
            ho[t * HH + j] = hh;
        }
        xp = xp_next;
        __syncthreads();
    }
    // ---- MIL attention: scores (wa1T coalesced loads) ----
    int wave = tid >> 6;
    for (int t = wave; t < TT; t += 7) {
        float a = 0.f;
        if (lane < DD) {
            float s = ba1[lane];
            #pragma unroll
            for (int h2 = 0; h2 < HH; h2 += 4) {
                float4 h4v = *(const float4*)&ho[t*HH + h2];
                s += wa1T[(h2+0)*DD + lane]*h4v.x + wa1T[(h2+1)*DD + lane]*h4v.y
                   + wa1T[(h2+2)*DD + lane]*h4v.z + wa1T[(h2+3)*DD + lane]*h4v.w;
            }
            a = tanh_fast(s) * wa2[lane];
        }
        #pragma unroll
        for (int off = 32; off; off >>= 1) a += __shfl_down(a, off, 64);
        if (lane == 0) sc[t] = a + ba2[0];
    }
    __syncthreads();
    if (tid < 64) {
        float v = (lane < TT) ? sc[lane] : -1e30f;
        if (lane < TT) out[BB*NC + b*TT + lane] = v;      // Att (pre-softmax logits)
        float m = v;
        #pragma unroll
        for (int off = 32; off; off >>= 1) m = fmaxf(m, __shfl_xor(m, off, 64));
        float e = (lane < TT) ? __expf(v - m) : 0.f;
        float s = e;
        #pragma unroll
        for (int off = 32; off; off >>= 1) s += __shfl_xor(s, off, 64);
        if (lane < TT) p[lane] = e / s;
    }
    __syncthreads();
    if (tid < HH) {
        float m = 0.f;
        #pragma unroll
        for (int t = 0; t < TT; t++) m += p[t] * ho[t*HH + tid];
        M[tid] = m;
    }
    __syncthreads();
    // ---- classifier: wave-parallel dot (was serial on thread 0) ----
    if (tid < 64) {
        float l0p = 0.f, l1p = 0.f;
        for (int h2 = lane; h2 < HH; h2 += 64) {
            float m = M[h2];
            l0p += m * wc[h2];
            l1p += m * wc[HH + h2];
        }
        #pragma unroll
        for (int off = 32; off; off >>= 1) {
            l0p += __shfl_down(l0p, off, 64);
            l1p += __shfl_down(l1p, off, 64);
        }
        if (lane == 0) {
            float l0 = l0p + bc[0], l1 = l1p + bc[1];
            float mx = fmaxf(l0, l1);
            float e0 = __expf(l0 - mx), e1 = __expf(l1 - mx);
            float s = e0 + e1;
            out[b*NC + 0] = e0 / s;
            out[b*NC + 1] = e1 / s;
        }
    }
}

extern "C" void kernel_launch(void* const* d_in, const int* in_sizes, int n_in,
                              void* d_out, int out_size, void* d_ws, size_t ws_size,
                              hipStream_t stream) {
    const float* x     = (const float*)d_in[0];
    const float* w_gcn = (const float*)d_in[1];
    const float* b_gcn = (const float*)d_in[2];
    const float* W_ih  = (const float*)d_in[3];
    const float* W_hh  = (const float*)d_in[4];
    const float* b_ih  = (const float*)d_in[5];
    const float* b_hh  = (const float*)d_in[6];
    const float* wa1   = (const float*)d_in[7];
    const float* ba1   = (const float*)d_in[8];
    const float* wa2   = (const float*)d_in[9];
    const float* ba2   = (const float*)d_in[10];
    const float* wc    = (const float*)d_in[11];
    const float* bc    = (const float*)d_in[12];
    float* out = (float*)d_out;
    float* ws  = (float*)d_ws;

    float* gout  = ws;                       // 552960 floats
    float* Wt    = gout + 552960;            // 144000 floats
    float* xproj = Wt + 144000;              // 614400 floats
    float* wa1T  = xproj + 614400;           // 6400 floats

    transpose_kernel<<<(NN*G4 + DD*HH + 255)/256, 256, 0, stream>>>(W_ih, Wt, wa1, wa1T);
    gcn_kernel<<<768, 256, 0, stream>>>(x, w_gcn, b_gcn, gout);
    xproj_kernel<<<384, 448, 0, stream>>>(gout, Wt, b_ih, b_hh, xproj);
    lstm_attn_kernel<<<BB, 448, 0, stream>>>(xproj, W_hh, wa1T, ba1, wa2, ba2, wc, bc, out);
}